// Round 5
// baseline (2345.391 us; speedup 1.0000x reference)
//
#include <hip/hip_runtime.h>
#include <stdint.h>

// Farthest Point Sampling, B=8, N=131072, npoint=1024.
// 8 batches x 32 WGs x 256 threads (all 256 CUs). Coordinates live in LDS
// (48 KB SoA per WG) -- rounds 2-4 proved hipcc rematerializes invariant
// global loads per-iteration instead of keeping them in VGPRs; LDS reads
// can't be remat'd and ds_read_b128 is 12cy throughput at 4 waves/CU.
// dist[16] stays in VGPRs (loop-carried dependency -> never spilled, per r4).
// Cross-WG per-iteration sync via tagged, cache-line-padded slots in d_ws
// (relaxed agent-scope atomics -- the 64-bit slot word is the entire payload).

#define NPTS        131072
#define NBATCH      8
#define WGB         32          // workgroups per batch
#define THREADS     256
#define PPW         4096        // points per WG
#define SLOT_STRIDE 16          // ULLs per slot = 128 B (own cache line)
#define BIGDIST     1e10f

__global__ __launch_bounds__(THREADS, 1) void fps_kernel(
        const float* __restrict__ xyz,          // [B, N, 3]
        int* __restrict__ out,                  // [B, npoint]
        unsigned long long* __restrict__ slots, // [2][NBATCH][WGB][SLOT_STRIDE]
        int npoint)
{
    const int bid  = blockIdx.x;
    const int b    = bid & (NBATCH - 1);  // batch; its 32 WGs on one XCD (heuristic)
    const int w    = bid >> 3;            // 0..31 WG-within-batch
    const int tid  = threadIdx.x;
    const int lane = tid & 63;
    const int wave = tid >> 6;            // 0..3

    const float* base = xyz + (size_t)b * NPTS * 3;
    const int q0 = w * PPW;               // first batch-point of this WG

    // ---- LDS: SoA coords for this WG's 4096 points (48 KB) ----
    __shared__ __align__(16) float x_lds[PPW];
    __shared__ __align__(16) float y_lds[PPW];
    __shared__ __align__(16) float z_lds[PPW];
    __shared__ unsigned long long s_w[THREADS / 64];
    __shared__ float s_c[3];

    // ---- one-time fill: thread t loads points t+256j (coalesced-ish) ----
    #pragma unroll
    for (int j = 0; j < 16; ++j) {
        int q = tid + 256 * j;                      // 0..4095 within WG
        const float* p = base + (size_t)(q0 + q) * 3;
        x_lds[q] = p[0];
        y_lds[q] = p[1];
        z_lds[q] = p[2];
    }

    // dist registers: thread t covers points q = 4t + 1024g + e  (g,e in 0..3),
    // ascending q as (g,e) ascend -> strict '>' keeps first max (argmax tie rule).
    float dist[16];
    #pragma unroll
    for (int j = 0; j < 16; ++j) dist[j] = BIGDIST;

    // initial centroid = point 0 of this batch
    float cx = base[0], cy = base[1], cz = base[2];

    if (w == 0 && tid == 0) out[b * npoint + 0] = 0;

    const size_t PAR = (size_t)NBATCH * WGB * SLOT_STRIDE;  // parity block (ULLs)

    __syncthreads();   // fill visible to all waves

    for (int i = 0; i < npoint - 1; ++i) {
        // ---- distance min-update + per-thread argmax (LDS b128 + VALU) ----
        float bv = -1.0f; int bq = 0;   // bq: point index within WG (0..4095)
        {
            #pragma clang fp contract(off)
            #pragma unroll
            for (int g = 0; g < 4; ++g) {
                const int qg = 4 * tid + 1024 * g;
                float4 xv = *reinterpret_cast<const float4*>(&x_lds[qg]);
                float4 yv = *reinterpret_cast<const float4*>(&y_lds[qg]);
                float4 zv = *reinterpret_cast<const float4*>(&z_lds[qg]);
                float xs[4] = { xv.x, xv.y, xv.z, xv.w };
                float ys[4] = { yv.x, yv.y, yv.z, yv.w };
                float zs[4] = { zv.x, zv.y, zv.z, zv.w };
                #pragma unroll
                for (int e = 0; e < 4; ++e) {
                    const int j = 4 * g + e;
                    float dx = xs[e] - cx, dy = ys[e] - cy, dz = zs[e] - cz;
                    float d  = dx*dx + dy*dy + dz*dz;   // mul/add order matches np ref
                    float nd = fminf(dist[j], d);
                    dist[j]  = nd;
                    if (nd > bv) { bv = nd; bq = qg + e; }
                }
            }
        }
        // pack: [63:32] float bits (non-neg -> order-preserving)
        //       [16:0]  131071 - idx  (bigger packed == smaller idx on tie)
        //       bits [31:22] hold the tag at publish time (zero here)
        unsigned long long pk =
              ((unsigned long long)__float_as_uint(bv) << 32)
            | (unsigned long long)(0x1FFFFu - (unsigned)(q0 + bq));

        // ---- wave butterfly max on packed u64 ----
        #pragma unroll
        for (int m = 32; m >= 1; m >>= 1) {
            unsigned long long o = __shfl_xor(pk, m);
            if (o > pk) pk = o;
        }
        if (lane == 0) s_w[wave] = pk;
        __syncthreads();

        unsigned long long* sb =
            slots + ((i & 1) ? PAR : (size_t)0) + (size_t)b * WGB * SLOT_STRIDE;
        const unsigned tag = (unsigned)(i + 1);   // 1..1023, fits 10 bits, never 0

        if (wave == 0) {
            // ---- cross-wave reduce over the 4 wave results ----
            unsigned long long v = s_w[lane & 3];
            #pragma unroll
            for (int m = 2; m >= 1; m >>= 1) {
                unsigned long long o = __shfl_xor(v, m);
                if (o > v) v = o;
            }
            // ---- lane 0 publishes (tag in bits [31:22]); relaxed suffices:
            //      the slot word is the entire communicated payload ----
            if (lane == 0) {
                unsigned long long pub = v | ((unsigned long long)tag << 22);
                __hip_atomic_store(sb + (size_t)w * SLOT_STRIDE, pub,
                                   __ATOMIC_RELAXED, __HIP_MEMORY_SCOPE_AGENT);
            }
            // ---- lanes 0..31 poll the 32 padded slots ----
            unsigned long long s = 0;
            if (lane < WGB) {
                unsigned long long* sl = sb + (size_t)lane * SLOT_STRIDE;
                do {
                    s = __hip_atomic_load(sl, __ATOMIC_RELAXED,
                                          __HIP_MEMORY_SCOPE_AGENT);
                } while (((unsigned)(s >> 22) & 1023u) != tag);
            }
            // speculative candidate-coords fetch (overlaps the reduce)
            int idx_l = (int)(0x1FFFFu - (unsigned)(s & 0x1FFFFu));
            float ccx = 0.f, ccy = 0.f, ccz = 0.f;
            if (lane < WGB) {
                const float* cp = base + (size_t)idx_l * 3;
                ccx = cp[0]; ccy = cp[1]; ccz = cp[2];
            }
            // ---- reduce over the 32 slot values (same tag -> order by val,idx) ----
            unsigned long long mx = s;
            #pragma unroll
            for (int m = 16; m >= 1; m >>= 1) {
                unsigned long long o = __shfl_xor(mx, m);
                if (o > mx) mx = o;
            }
            unsigned long long ball = __ballot(lane < WGB && s == mx);
            int winlane = __ffsll(ball) - 1;
            float wx = __shfl(ccx, winlane);
            float wy = __shfl(ccy, winlane);
            float wz = __shfl(ccz, winlane);
            int  wix = __shfl(idx_l, winlane);
            if (lane == 0) {
                s_c[0] = wx; s_c[1] = wy; s_c[2] = wz;
                if (w == 0) out[b * npoint + (i + 1)] = wix;
            }
        }
        __syncthreads();

        cx = s_c[0]; cy = s_c[1]; cz = s_c[2];
    }
}

extern "C" void kernel_launch(void* const* d_in, const int* in_sizes, int n_in,
                              void* d_out, int out_size, void* d_ws, size_t ws_size,
                              hipStream_t stream) {
    const float* xyz = (const float*)d_in[0];
    int* out = (int*)d_out;
    unsigned long long* slots = (unsigned long long*)d_ws;
    const int npoint = out_size / NBATCH;   // 1024

    // Clear slot region (64 KB) so stale/poisoned tags can never match tag>=1.
    hipMemsetAsync(d_ws, 0,
                   (size_t)2 * NBATCH * WGB * SLOT_STRIDE * sizeof(unsigned long long),
                   stream);

    dim3 grid(NBATCH * WGB);   // 256 WGs <= 256 CUs -> all co-resident, spin-sync safe
    dim3 block(THREADS);
    fps_kernel<<<grid, block, 0, stream>>>(xyz, out, slots, npoint);
}